// Round 7
// baseline (298.707 us; speedup 1.0000x reference)
//
#include <hip/hip_runtime.h>
#include <hip/hip_bf16.h>

#define B_ 32
#define T_ 40
#define P_ 256
#define V_ 4096
#define D_ 256
#define DINO_ 384
#define H_ 4
#define L_ 2
#define HD_ 64
#define DFF_ 1024
#define EPS_ 1e-5f

typedef __bf16 bf16;
typedef __bf16 bf16x8 __attribute__((ext_vector_type(8)));
typedef float f32x4 __attribute__((ext_vector_type(4)));

// bf16 weight arena offsets (elements)
#define OFF_QKV 0            // 2 x 768*256
#define OFF_OUTW 393216      // 2 x 256*256
#define OFF_W1 524288        // 2 x 1024*256
#define OFF_W2 1048576       // 2 x 256*1024
#define OFF_FUS 1572864      // 256*640
#define WB_TOTAL 1736704
#define CONV_BLOCKS 848      // WB_TOTAL / 2048
#define PAT_BLOCKS 1536      // 32*256*384 / 2048

__device__ __forceinline__ bf16x8 cvt8(const float* p) {
  float4 f0 = *(const float4*)p;
  float4 f1 = *(const float4*)(p + 4);
  bf16x8 v;
  v[0] = (bf16)f0.x; v[1] = (bf16)f0.y; v[2] = (bf16)f0.z; v[3] = (bf16)f0.w;
  v[4] = (bf16)f1.x; v[5] = (bf16)f1.y; v[6] = (bf16)f1.z; v[7] = (bf16)f1.w;
  return v;
}

// ---- prep: embed | fus_w2 transpose->bf16 | weights->bf16 | patches->bf16 --
__global__ __launch_bounds__(256) void prep_k(
    const int* __restrict__ tokens, const float* __restrict__ tok_emb,
    const float* __restrict__ pos_emb, float* __restrict__ x,
    const float* __restrict__ fus_w2, bf16* __restrict__ w2Tb,
    const float* __restrict__ qkv_w, const float* __restrict__ out_w,
    const float* __restrict__ w1, const float* __restrict__ w2,
    const float* __restrict__ fus_w1, bf16* __restrict__ wb,
    const float* __restrict__ patches, bf16* __restrict__ patb) {
  __shared__ float tile[32][33];
  int bi = blockIdx.x;
  int tid = threadIdx.x;
  if (bi < B_ * T_) {
    int t = bi % T_;
    x[bi * D_ + tid] = tok_emb[tokens[bi] * D_ + tid] + pos_emb[t * D_ + tid];
  } else if (bi < B_ * T_ + 64) {
    int tt = bi - B_ * T_;
    int bx = (tt & 7) * 32, by = (tt >> 3) * 32;
    int tx = tid & 31, ty = tid >> 5;  // 32 x 8
#pragma unroll
    for (int i = 0; i < 32; i += 8) tile[ty + i][tx] = fus_w2[(by + ty + i) * D_ + bx + tx];
    __syncthreads();
#pragma unroll
    for (int i = 0; i < 32; i += 8)
      w2Tb[(bx + ty + i) * D_ + by + tx] = (bf16)tile[tx][ty + i];
  } else if (bi < B_ * T_ + 64 + CONV_BLOCKS) {
    long f = (long)(bi - B_ * T_ - 64) * 2048 + tid * 8;
    const float* src;
    long off;
    if (f < OFF_OUTW)      { src = qkv_w;  off = f - OFF_QKV; }
    else if (f < OFF_W1)   { src = out_w;  off = f - OFF_OUTW; }
    else if (f < OFF_W2)   { src = w1;     off = f - OFF_W1; }
    else if (f < OFF_FUS)  { src = w2;     off = f - OFF_W2; }
    else                   { src = fus_w1; off = f - OFF_FUS; }
    *(bf16x8*)&wb[f] = cvt8(src + off);
  } else {
    long f = (long)(bi - B_ * T_ - 64 - CONV_BLOCKS) * 2048 + tid * 8;
    *(bf16x8*)&patb[f] = cvt8(patches + f);
  }
}

// ---- staged MFMA GEMM, 32x32 tile, 4 waves; optional LN-on-A / resid / relu
// ALN: A = LayerNorm(S rows) computed in staging (K must be 256).
// WLN: blocks with blockIdx.x==0 write normalized rows (f32) to xlnout.
// RESID: epilogue += resid[m*256+n] (only for N=256 gemms).
template <int ALN, int ABF16, int OBF16, int RELU, int RESID, int WLN>
__global__ __launch_bounds__(256) void gemm_k(
    const void* __restrict__ Av, const bf16* __restrict__ W,
    const float* __restrict__ bias, const float* __restrict__ lng,
    const float* __restrict__ lnb, const float* __restrict__ resid,
    float* __restrict__ xlnout, void* __restrict__ outv,
    int K, int lda, int ldw, int ldc) {
  __shared__ bf16 As[32 * 264];
  __shared__ bf16 Ws[32 * 72];
  const int tid = threadIdx.x;
  const int lane = tid & 63;
  const int wv = tid >> 6;
  const int mi = wv & 1, ni = wv >> 1;
  const int col = lane & 15, quad = lane >> 4;
  const int bn = blockIdx.x * 32, bm = blockIdx.y * 32;
  const int srow = tid >> 3, kc = (tid & 7) * 8;
  const bf16* Wp = W + (long)(bn + srow) * ldw + kc;
  f32x4 acc = {0.f, 0.f, 0.f, 0.f};

  if (ALN) {
    // LayerNorm staging: full K=256 A-panel (ld 264)
    const float* S = (const float*)Av;
    const int r = srow, cg = (tid & 7) * 32;
    const float* sp = S + (long)(bm + r) * lda + cg;
    float v[32];
    float sum = 0.f, ss = 0.f;
#pragma unroll
    for (int i = 0; i < 8; ++i) {
      float4 f = *(const float4*)(sp + i * 4);
      v[i*4] = f.x; v[i*4+1] = f.y; v[i*4+2] = f.z; v[i*4+3] = f.w;
      sum += f.x + f.y + f.z + f.w;
      ss += f.x*f.x + f.y*f.y + f.z*f.z + f.w*f.w;
    }
#pragma unroll
    for (int mk = 1; mk < 8; mk <<= 1) {
      sum += __shfl_xor(sum, mk);
      ss += __shfl_xor(ss, mk);
    }
    float mean = sum * (1.0f / D_);
    float inv = rsqrtf(ss * (1.0f / D_) - mean * mean + EPS_);
#pragma unroll
    for (int i = 0; i < 8; ++i) {
      float4 g4 = *(const float4*)(lng + cg + i * 4);
      float4 b4 = *(const float4*)(lnb + cg + i * 4);
      float n0 = (v[i*4]   - mean) * inv * g4.x + b4.x;
      float n1 = (v[i*4+1] - mean) * inv * g4.y + b4.y;
      float n2 = (v[i*4+2] - mean) * inv * g4.z + b4.z;
      float n3 = (v[i*4+3] - mean) * inv * g4.w + b4.w;
      As[r * 264 + cg + i*4]     = (bf16)n0;
      As[r * 264 + cg + i*4 + 1] = (bf16)n1;
      As[r * 264 + cg + i*4 + 2] = (bf16)n2;
      As[r * 264 + cg + i*4 + 3] = (bf16)n3;
      if (WLN) {
        if (blockIdx.x == 0) {
          float4 o; o.x = n0; o.y = n1; o.z = n2; o.w = n3;
          *(float4*)&xlnout[(long)(bm + r) * D_ + cg + i*4] = o;
        }
      }
    }
    __syncthreads();
    for (int kk = 0; kk < 256; kk += 64) {
      *(bf16x8*)&Ws[srow * 72 + kc] = *(const bf16x8*)(Wp + kk);
      __syncthreads();
#pragma unroll
      for (int ki = 0; ki < 2; ++ki) {
        bf16x8 afr = *(const bf16x8*)&As[(mi*16 + col) * 264 + kk + ki*32 + quad*8];
        bf16x8 bfr = *(const bf16x8*)&Ws[(ni*16 + col) * 72 + ki*32 + quad*8];
        acc = __builtin_amdgcn_mfma_f32_16x16x32_bf16(afr, bfr, acc, 0, 0, 0);
      }
      __syncthreads();
    }
  } else {
    const float* Af = (const float*)Av;
    const bf16* Ab = (const bf16*)Av;
    for (int kk = 0; kk < K; kk += 64) {
      if (ABF16)
        *(bf16x8*)&As[srow * 72 + kc] = *(const bf16x8*)(Ab + (long)(bm + srow) * lda + kk + kc);
      else
        *(bf16x8*)&As[srow * 72 + kc] = cvt8(Af + (long)(bm + srow) * lda + kk + kc);
      *(bf16x8*)&Ws[srow * 72 + kc] = *(const bf16x8*)(Wp + kk);
      __syncthreads();
#pragma unroll
      for (int ki = 0; ki < 2; ++ki) {
        bf16x8 afr = *(const bf16x8*)&As[(mi*16 + col) * 72 + ki*32 + quad*8];
        bf16x8 bfr = *(const bf16x8*)&Ws[(ni*16 + col) * 72 + ki*32 + quad*8];
        acc = __builtin_amdgcn_mfma_f32_16x16x32_bf16(afr, bfr, acc, 0, 0, 0);
      }
      __syncthreads();
    }
  }

  const int n = bn + ni * 16 + col;
  float bv = bias ? bias[n] : 0.0f;
#pragma unroll
  for (int r4 = 0; r4 < 4; ++r4) {
    int m = bm + mi * 16 + quad * 4 + r4;
    float val = acc[r4] + bv;
    if (RESID) val += resid[(long)m * D_ + n];
    if (RELU) val = fmaxf(val, 0.0f);
    if (OBF16) ((bf16*)outv)[(long)m * ldc + n] = (bf16)val;
    else ((float*)outv)[(long)m * ldc + n] = val;
  }
}

// ---- fused pproj/cproj/weff; cproj has shift+LN folded into A-staging -----
__global__ __launch_bounds__(256) void fuse3_k(
    const bf16* __restrict__ patb, const float* __restrict__ s2,
    const float* __restrict__ lng, const float* __restrict__ lnb,
    const float* __restrict__ cls_w, const bf16* __restrict__ fusb,
    const bf16* __restrict__ w2Tb, const float* __restrict__ fus_b1,
    const int* __restrict__ tokens, float* __restrict__ pprojT,
    float* __restrict__ cw) {
  __shared__ bf16 As[32 * 264];
  __shared__ bf16 Ws[32 * 72];
  const int tid = threadIdx.x;
  const int lane = tid & 63;
  const int wv = tid >> 6;
  const int mi = wv & 1, ni = wv >> 1;
  const int col = lane & 15, quad = lane >> 4;
  const int bn = blockIdx.x * 32;
  const int y = blockIdx.y;
  const int srow = tid >> 3, kc = (tid & 7) * 8;

  int job, bm;
  if (y < 256) { job = 0; bm = y * 32; }
  else if (y < 296) { job = 1; bm = (y - 256) * 32; }
  else { job = 2; bm = (y - 296) * 32; }

  f32x4 acc = {0.f, 0.f, 0.f, 0.f};

  if (job == 1) {
    // A = shift(ln(s2)) rows, full K=256 panel
    const int r = srow, cg = (tid & 7) * 32;
    const int gm = bm + r;
    const int t = gm % T_;
    if (t == 0) {
      bf16x8 z8 = {};
#pragma unroll
      for (int i = 0; i < 4; ++i) *(bf16x8*)&As[r * 264 + cg + i * 8] = z8;
    } else {
      const float* sp = s2 + (long)(gm - 1) * D_ + cg;
      float v[32];
      float sum = 0.f, ss = 0.f;
#pragma unroll
      for (int i = 0; i < 8; ++i) {
        float4 f = *(const float4*)(sp + i * 4);
        v[i*4] = f.x; v[i*4+1] = f.y; v[i*4+2] = f.z; v[i*4+3] = f.w;
        sum += f.x + f.y + f.z + f.w;
        ss += f.x*f.x + f.y*f.y + f.z*f.z + f.w*f.w;
      }
#pragma unroll
      for (int mk = 1; mk < 8; mk <<= 1) {
        sum += __shfl_xor(sum, mk);
        ss += __shfl_xor(ss, mk);
      }
      float mean = sum * (1.0f / D_);
      float inv = rsqrtf(ss * (1.0f / D_) - mean * mean + EPS_);
#pragma unroll
      for (int i = 0; i < 8; ++i) {
        float4 g4 = *(const float4*)(lng + cg + i * 4);
        float4 b4 = *(const float4*)(lnb + cg + i * 4);
        As[r*264 + cg + i*4]     = (bf16)((v[i*4]   - mean) * inv * g4.x + b4.x);
        As[r*264 + cg + i*4 + 1] = (bf16)((v[i*4+1] - mean) * inv * g4.y + b4.y);
        As[r*264 + cg + i*4 + 2] = (bf16)((v[i*4+2] - mean) * inv * g4.z + b4.z);
        As[r*264 + cg + i*4 + 3] = (bf16)((v[i*4+3] - mean) * inv * g4.w + b4.w);
      }
    }
    __syncthreads();
    const bf16* Wp = fusb + 384 + (long)(bn + srow) * 640 + kc;
    for (int kk = 0; kk < 256; kk += 64) {
      *(bf16x8*)&Ws[srow * 72 + kc] = *(const bf16x8*)(Wp + kk);
      __syncthreads();
#pragma unroll
      for (int ki = 0; ki < 2; ++ki) {
        bf16x8 afr = *(const bf16x8*)&As[(mi*16 + col) * 264 + kk + ki*32 + quad*8];
        bf16x8 bfr = *(const bf16x8*)&Ws[(ni*16 + col) * 72 + ki*32 + quad*8];
        acc = __builtin_amdgcn_mfma_f32_16x16x32_bf16(afr, bfr, acc, 0, 0, 0);
      }
      __syncthreads();
    }
  } else {
    const bf16* Wp;
    int K;
    if (job == 0) { Wp = fusb + (long)(bn + srow) * 640 + kc; K = DINO_; }
    else          { Wp = w2Tb + (long)(bn + srow) * D_ + kc;  K = D_; }
    for (int kk = 0; kk < K; kk += 64) {
      if (job == 0)
        *(bf16x8*)&As[srow * 72 + kc] =
            *(const bf16x8*)(patb + (long)(bm + srow) * DINO_ + kk + kc);
      else
        *(bf16x8*)&As[srow * 72 + kc] =
            cvt8(cls_w + (long)tokens[bm + srow] * D_ + kk + kc);
      *(bf16x8*)&Ws[srow * 72 + kc] = *(const bf16x8*)(Wp + kk);
      __syncthreads();
#pragma unroll
      for (int ki = 0; ki < 2; ++ki) {
        bf16x8 afr = *(const bf16x8*)&As[(mi*16 + col) * 72 + ki*32 + quad*8];
        bf16x8 bfr = *(const bf16x8*)&Ws[(ni*16 + col) * 72 + ki*32 + quad*8];
        acc = __builtin_amdgcn_mfma_f32_16x16x32_bf16(afr, bfr, acc, 0, 0, 0);
      }
      __syncthreads();
    }
  }

  const int n = bn + ni * 16 + col;
  if (job == 0) {
#pragma unroll
    for (int r4 = 0; r4 < 4; ++r4) {
      int m = bm + mi * 16 + quad * 4 + r4;
      int b = m >> 8, p = m & 255;
      pprojT[(long)b * (D_ * P_) + (long)n * P_ + p] = acc[r4];
    }
  } else if (job == 1) {
    float bv = fus_b1[n];
#pragma unroll
    for (int r4 = 0; r4 < 4; ++r4) {
      int m = bm + mi * 16 + quad * 4 + r4;
      cw[(long)m * (2 * D_) + n * 2] = acc[r4] + bv;
    }
  } else {
#pragma unroll
    for (int r4 = 0; r4 < 4; ++r4) {
      int m = bm + mi * 16 + quad * 4 + r4;
      cw[(long)m * (2 * D_) + n * 2 + 1] = acc[r4];
    }
  }
}

// ---- causal attention, one (b,h) per block --------------------------------
__global__ __launch_bounds__(256) void attn_k(const float* __restrict__ qkv,
                                              float* __restrict__ ctx) {
  __shared__ float q[T_][HD_ + 1];
  __shared__ float k[T_][HD_ + 1];
  __shared__ float v[T_][HD_ + 1];
  __shared__ float s[T_][T_ + 1];
  int h = blockIdx.x, b = blockIdx.y;
  int tid = threadIdx.x;
  for (int idx = tid; idx < T_ * HD_; idx += 256) {
    int t = idx >> 6, d = idx & 63;
    long base = (long)(b * T_ + t) * (3 * D_) + h * HD_ + d;
    q[t][d] = qkv[base];
    k[t][d] = qkv[base + D_];
    v[t][d] = qkv[base + 2 * D_];
  }
  __syncthreads();
  for (int idx = tid; idx < T_ * T_; idx += 256) {
    int i = idx / T_, j = idx - i * T_;
    if (j <= i) {
      float acc = 0.f;
#pragma unroll
      for (int d = 0; d < HD_; ++d) acc += q[i][d] * k[j][d];
      s[i][j] = acc * 0.125f;
    }
  }
  __syncthreads();
  if (tid < T_) {
    int i = tid;
    float mx = -1e30f;
    for (int j = 0; j <= i; ++j) mx = fmaxf(mx, s[i][j]);
    float sum = 0.f;
    for (int j = 0; j <= i; ++j) {
      float e = __expf(s[i][j] - mx);
      s[i][j] = e;
      sum += e;
    }
    float inv = 1.0f / sum;
    for (int j = 0; j <= i; ++j) s[i][j] *= inv;
  }
  __syncthreads();
  for (int idx = tid; idx < T_ * HD_; idx += 256) {
    int i = idx >> 6, d = idx & 63;
    float acc = 0.f;
    for (int j = 0; j <= i; ++j) acc += s[i][j] * v[j][d];
    ctx[(long)(b * T_ + i) * D_ + h * HD_ + d] = acc;
  }
}

// ---- final: out[b,p,t] = sigmoid(sum_e gelu(pp+cp)*we + beff) -------------
__global__ __launch_bounds__(256) void final_k(const float* __restrict__ pprojT,
                                               const float* __restrict__ cw,
                                               const int* __restrict__ tokens,
                                               const float* __restrict__ cls_w,
                                               const float* __restrict__ cls_b,
                                               const float* __restrict__ fus_b2,
                                               float* __restrict__ out) {
  __shared__ float2 cws[4][D_];
  int tid = threadIdx.x;
  int lane = tid & 63, wv = tid >> 6;
  int p = blockIdx.x * 64 + lane;
  int t = blockIdx.y * 4 + wv;
  int b = blockIdx.z;
  int mbase = b * T_ + blockIdx.y * 4;
  for (int idx = tid; idx < 4 * D_; idx += 256) {
    int tt = idx >> 8, e = idx & 255;
    cws[tt][e] = ((const float2*)cw)[(long)(mbase + tt) * D_ + e];
  }
  __syncthreads();

  int m = b * T_ + t;
  int tok = tokens[m];
  const float* cr = cls_w + (long)tok * D_;
  float bacc = 0.f;
#pragma unroll
  for (int i = 0; i < 4; ++i) bacc += cr[lane + i * 64] * fus_b2[lane + i * 64];
#pragma unroll
  for (int mk = 1; mk < 64; mk <<= 1) bacc += __shfl_xor(bacc, mk);
  float beff = bacc + cls_b[tok];

  const float* ppb = pprojT + (long)b * (D_ * P_);  // [e][p]
  float acc = 0.f;
#pragma unroll 8
  for (int e = 0; e < D_; ++e) {
    float pp = ppb[e * P_ + p];
    float2 c = cws[wv][e];
    float x = pp + c.x;
    float x2 = x * x;
    float u = x * fmaf(-0.1029432f, x2, -2.3022083f);  // -log2e*1.5958*(x+0.044715x^3)
    float ex = __builtin_amdgcn_exp2f(u);
    float r = __builtin_amdgcn_rcpf(1.0f + ex);
    acc = fmaf(x * r, c.y, acc);
  }
  float logit = acc + beff;
  float es = __builtin_amdgcn_exp2f(-1.4426950408889634f * logit);
  out[(long)(b * P_ + p) * T_ + t] = __builtin_amdgcn_rcpf(1.0f + es);
}

extern "C" void kernel_launch(void* const* d_in, const int* in_sizes, int n_in, void* d_out,
                              int out_size, void* d_ws, size_t ws_size, hipStream_t stream) {
  const float* patches = (const float*)d_in[0];
  const int* tokens = (const int*)d_in[1];
  const float* tok_emb = (const float*)d_in[2];
  const float* pos_emb = (const float*)d_in[3];
  const float* qkv_w = (const float*)d_in[4];
  const float* qkv_b = (const float*)d_in[5];
  const float* out_w = (const float*)d_in[6];
  const float* out_b = (const float*)d_in[7];
  const float* ln1_s = (const float*)d_in[8];
  const float* ln1_b = (const float*)d_in[9];
  const float* w1 = (const float*)d_in[10];
  const float* b1 = (const float*)d_in[11];
  const float* w2 = (const float*)d_in[12];
  const float* b2 = (const float*)d_in[13];
  const float* ln2_s = (const float*)d_in[14];
  const float* ln2_b = (const float*)d_in[15];
  const float* fus_w1 = (const float*)d_in[16];
  const float* fus_b1 = (const float*)d_in[17];
  const float* fus_w2 = (const float*)d_in[18];
  const float* fus_b2 = (const float*)d_in[19];
  const float* cls_w = (const float*)d_in[20];
  const float* cls_b = (const float*)d_in[21];
  float* out = (float*)d_out;

  const int MT = B_ * T_;  // 1280
  float* x0 = (float*)d_ws;                 // 1280*256
  float* qkvbuf = x0 + MT * D_;             // 1280*768
  float* attbuf = qkvbuf + MT * 3 * D_;     // 1280*256
  float* s1 = attbuf + MT * D_;             // 1280*256
  float* xln1 = s1 + MT * D_;               // 1280*256
  float* s2 = xln1 + MT * D_;               // 1280*256
  float* xln2 = s2 + MT * D_;               // 1280*256
  float* pprojT = xln2 + MT * D_;           // 32*256*256 [b][e][p]
  float* cwbuf = pprojT + (long)B_ * D_ * P_;  // 1280*512
  bf16* wb = (bf16*)(cwbuf + MT * D_ * 2);  // weight arena
  bf16* w2Tb = wb + WB_TOTAL;               // 256*256
  bf16* patb = w2Tb + D_ * D_;              // 32*256*384
  bf16* hb = patb + (long)B_ * P_ * DINO_;  // 1280*1024 bf16

  prep_k<<<MT + 64 + CONV_BLOCKS + PAT_BLOCKS, 256, 0, stream>>>(
      tokens, tok_emb, pos_emb, x0, fus_w2, w2Tb, qkv_w, out_w, w1, w2, fus_w1, wb,
      patches, patb);

  for (int l = 0; l < L_; ++l) {
    const float* xin = (l == 0) ? x0 : s2;          // pre-LN2 of prev layer (l>0)
    const float* presid = (l == 0) ? x0 : xln2;     // residual for proj
    if (l == 0) {
      // qkv = x0 @ qkv_w^T + b (no LN)
      gemm_k<0,0,0,0,0,0><<<dim3(24, 40), 256, 0, stream>>>(
          x0, wb + OFF_QKV, qkv_b, nullptr, nullptr, nullptr, nullptr, qkvbuf,
          D_, D_, D_, 3 * D_);
    } else {
      // qkv = ln2_0(s2) @ qkv_w^T + b ; bn0 writes xln2
      gemm_k<1,0,0,0,0,1><<<dim3(24, 40), 256, 0, stream>>>(
          s2, wb + OFF_QKV + (long)l * 3 * D_ * D_, qkv_b + l * 3 * D_,
          ln2_s, ln2_b, nullptr, xln2, qkvbuf, D_, D_, D_, 3 * D_);
    }
    attn_k<<<dim3(H_, B_), 256, 0, stream>>>(qkvbuf, attbuf);
    // s1 = att @ out_w^T + out_b + x_prev
    gemm_k<0,0,0,0,1,0><<<dim3(8, 40), 256, 0, stream>>>(
        attbuf, wb + OFF_OUTW + (long)l * D_ * D_, out_b + l * D_,
        nullptr, nullptr, presid, nullptr, s1, D_, D_, D_, D_);
    // h = relu(ln1(s1) @ w1^T + b1) -> bf16 ; bn0 writes xln1
    gemm_k<1,0,1,1,0,1><<<dim3(32, 40), 256, 0, stream>>>(
        s1, wb + OFF_W1 + (long)l * DFF_ * D_, b1 + l * DFF_,
        ln1_s + l * D_, ln1_b + l * D_, nullptr, xln1, hb, D_, D_, D_, DFF_);
    // s2 = h @ w2^T + b2 + xln1
    gemm_k<0,1,0,0,1,0><<<dim3(8, 40), 256, 0, stream>>>(
        hb, wb + OFF_W2 + (long)l * D_ * DFF_, b2 + l * D_,
        nullptr, nullptr, xln1, nullptr, s2, DFF_, DFF_, DFF_, D_);
  }

  fuse3_k<<<dim3(8, 336), 256, 0, stream>>>(patb, s2, ln2_s + D_, ln2_b + D_, cls_w,
                                            wb + OFF_FUS, w2Tb, fus_b1, tokens,
                                            pprojT, cwbuf);

  final_k<<<dim3(4, 10, 32), 256, 0, stream>>>(pprojT, cwbuf, tokens, cls_w, cls_b,
                                               fus_b2, out);
}

// Round 8
// 257.479 us; speedup vs baseline: 1.1601x; 1.1601x over previous
//
#include <hip/hip_runtime.h>
#include <hip/hip_bf16.h>

#define B_ 32
#define T_ 40
#define P_ 256
#define V_ 4096
#define D_ 256
#define DINO_ 384
#define H_ 4
#define L_ 2
#define HD_ 64
#define DFF_ 1024
#define EPS_ 1e-5f

typedef __bf16 bf16;
typedef __bf16 bf16x8 __attribute__((ext_vector_type(8)));
typedef float f32x4 __attribute__((ext_vector_type(4)));

// bf16 weight arena offsets (elements)
#define OFF_QKV 0            // 2 x 768*256
#define OFF_OUTW 393216      // 2 x 256*256
#define OFF_W1 524288        // 2 x 1024*256
#define OFF_W2 1048576       // 2 x 256*1024
#define OFF_FUS 1572864      // 256*640
#define WB_TOTAL 1736704
#define CONV_BLOCKS 848      // WB_TOTAL / 2048
#define PAT_BLOCKS 1536      // 32*256*384 / 2048

__device__ __forceinline__ bf16x8 cvt8(const float* p) {
  float4 f0 = *(const float4*)p;
  float4 f1 = *(const float4*)(p + 4);
  bf16x8 v;
  v[0] = (bf16)f0.x; v[1] = (bf16)f0.y; v[2] = (bf16)f0.z; v[3] = (bf16)f0.w;
  v[4] = (bf16)f1.x; v[5] = (bf16)f1.y; v[6] = (bf16)f1.z; v[7] = (bf16)f1.w;
  return v;
}

// ---- prep: embed | fus_w2 transpose->bf16 | weights->bf16 | patches->bf16 --
__global__ __launch_bounds__(256) void prep_k(
    const int* __restrict__ tokens, const float* __restrict__ tok_emb,
    const float* __restrict__ pos_emb, float* __restrict__ x,
    const float* __restrict__ fus_w2, bf16* __restrict__ w2Tb,
    const float* __restrict__ qkv_w, const float* __restrict__ out_w,
    const float* __restrict__ w1, const float* __restrict__ w2,
    const float* __restrict__ fus_w1, bf16* __restrict__ wb,
    const float* __restrict__ patches, bf16* __restrict__ patb) {
  __shared__ float tile[32][33];
  int bi = blockIdx.x;
  int tid = threadIdx.x;
  if (bi < B_ * T_) {
    int t = bi % T_;
    x[bi * D_ + tid] = tok_emb[tokens[bi] * D_ + tid] + pos_emb[t * D_ + tid];
  } else if (bi < B_ * T_ + 64) {
    int tt = bi - B_ * T_;
    int bx = (tt & 7) * 32, by = (tt >> 3) * 32;
    int tx = tid & 31, ty = tid >> 5;  // 32 x 8
#pragma unroll
    for (int i = 0; i < 32; i += 8) tile[ty + i][tx] = fus_w2[(by + ty + i) * D_ + bx + tx];
    __syncthreads();
#pragma unroll
    for (int i = 0; i < 32; i += 8)
      w2Tb[(bx + ty + i) * D_ + by + tx] = (bf16)tile[tx][ty + i];
  } else if (bi < B_ * T_ + 64 + CONV_BLOCKS) {
    long f = (long)(bi - B_ * T_ - 64) * 2048 + tid * 8;
    const float* src;
    long off;
    if (f < OFF_OUTW)      { src = qkv_w;  off = f - OFF_QKV; }
    else if (f < OFF_W1)   { src = out_w;  off = f - OFF_OUTW; }
    else if (f < OFF_W2)   { src = w1;     off = f - OFF_W1; }
    else if (f < OFF_FUS)  { src = w2;     off = f - OFF_W2; }
    else                   { src = fus_w1; off = f - OFF_FUS; }
    *(bf16x8*)&wb[f] = cvt8(src + off);
  } else {
    long f = (long)(bi - B_ * T_ - 64 - CONV_BLOCKS) * 2048 + tid * 8;
    *(bf16x8*)&patb[f] = cvt8(patches + f);
  }
}

// ---- staged MFMA GEMM: 32x32 tile, 4 waves; W bf16; optional resid/relu ----
// C[m,n] = act(A@W^T + bias [+ resid]); RESID requires ldc==256 layout.
template <int ABF16, int OBF16, int RELU, int RESID>
__global__ __launch_bounds__(256) void gemm_k(
    const void* __restrict__ Av, const bf16* __restrict__ W,
    const float* __restrict__ bias, const float* __restrict__ resid,
    void* __restrict__ outv, int K, int lda, int ldw, int ldc) {
  __shared__ bf16 As[32 * 72];
  __shared__ bf16 Ws[32 * 72];
  const int tid = threadIdx.x;
  const int lane = tid & 63;
  const int wv = tid >> 6;
  const int mi = wv & 1, ni = wv >> 1;
  const int col = lane & 15, quad = lane >> 4;
  const int bn = blockIdx.x * 32, bm = blockIdx.y * 32;
  const int srow = tid >> 3, kc = (tid & 7) * 8;
  const float* Af = (const float*)Av;
  const bf16* Ab = (const bf16*)Av;
  const bf16* Wp = W + (long)(bn + srow) * ldw + kc;

  f32x4 acc = {0.f, 0.f, 0.f, 0.f};
  for (int kk = 0; kk < K; kk += 64) {
    if (ABF16)
      *(bf16x8*)&As[srow * 72 + kc] = *(const bf16x8*)(Ab + (long)(bm + srow) * lda + kk + kc);
    else
      *(bf16x8*)&As[srow * 72 + kc] = cvt8(Af + (long)(bm + srow) * lda + kk + kc);
    *(bf16x8*)&Ws[srow * 72 + kc] = *(const bf16x8*)(Wp + kk);
    __syncthreads();
#pragma unroll
    for (int ki = 0; ki < 2; ++ki) {
      bf16x8 afr = *(const bf16x8*)&As[(mi * 16 + col) * 72 + ki * 32 + quad * 8];
      bf16x8 bfr = *(const bf16x8*)&Ws[(ni * 16 + col) * 72 + ki * 32 + quad * 8];
      acc = __builtin_amdgcn_mfma_f32_16x16x32_bf16(afr, bfr, acc, 0, 0, 0);
    }
    __syncthreads();
  }
  const int n = bn + ni * 16 + col;
  float bv = bias ? bias[n] : 0.0f;
#pragma unroll
  for (int r = 0; r < 4; ++r) {
    int m = bm + mi * 16 + quad * 4 + r;
    float val = acc[r] + bv;
    if (RESID) val += resid[(long)m * D_ + n];
    if (RELU) val = fmaxf(val, 0.0f);
    if (OBF16) ((bf16*)outv)[(long)m * ldc + n] = (bf16)val;
    else ((float*)outv)[(long)m * ldc + n] = val;
  }
}

// ---- LayerNorm: one wave per row, 4 rows/block, no LDS/barriers -----------
__global__ __launch_bounds__(256) void ln_k(const float* __restrict__ s,
                                            float* __restrict__ xout,
                                            const float* __restrict__ g,
                                            const float* __restrict__ be) {
  int wv = threadIdx.x >> 6, lane = threadIdx.x & 63;
  int m = blockIdx.x * 4 + wv;
  float4 v = *(const float4*)(s + (long)m * D_ + lane * 4);
  float sum = v.x + v.y + v.z + v.w;
  float ss = v.x * v.x + v.y * v.y + v.z * v.z + v.w * v.w;
#pragma unroll
  for (int mk = 1; mk < 64; mk <<= 1) {
    sum += __shfl_xor(sum, mk);
    ss += __shfl_xor(ss, mk);
  }
  float mean = sum * (1.0f / D_);
  float inv = rsqrtf(ss * (1.0f / D_) - mean * mean + EPS_);
  float4 g4 = *(const float4*)(g + lane * 4);
  float4 b4 = *(const float4*)(be + lane * 4);
  float4 o;
  o.x = (v.x - mean) * inv * g4.x + b4.x;
  o.y = (v.y - mean) * inv * g4.y + b4.y;
  o.z = (v.z - mean) * inv * g4.z + b4.z;
  o.w = (v.w - mean) * inv * g4.w + b4.w;
  *(float4*)(xout + (long)m * D_ + lane * 4) = o;
}

// ---- causal attention, (h, b, q-half) per block ----------------------------
__global__ __launch_bounds__(256) void attn_k(const float* __restrict__ qkv,
                                              float* __restrict__ ctx) {
  __shared__ float q[20][HD_ + 1];
  __shared__ float k[T_][HD_ + 1];
  __shared__ float v[T_][HD_ + 1];
  __shared__ float s[20][T_ + 1];
  int h = blockIdx.x, b = blockIdx.y, zq = blockIdx.z;
  int r0 = zq * 20;
  int tid = threadIdx.x;
  for (int idx = tid; idx < T_ * HD_; idx += 256) {
    int t = idx >> 6, d = idx & 63;
    long base = (long)(b * T_ + t) * (3 * D_) + h * HD_ + d;
    k[t][d] = qkv[base + D_];
    v[t][d] = qkv[base + 2 * D_];
    if (t < 20) q[t][d] = qkv[(long)(b * T_ + r0 + t) * (3 * D_) + h * HD_ + d];
  }
  __syncthreads();
  for (int idx = tid; idx < 20 * T_; idx += 256) {
    int i = idx / T_, j = idx - i * T_;
    if (j <= r0 + i) {
      float acc = 0.f;
#pragma unroll
      for (int d = 0; d < HD_; ++d) acc += q[i][d] * k[j][d];
      s[i][j] = acc * 0.125f;
    }
  }
  __syncthreads();
  if (tid < 20) {
    int i = tid, hi = r0 + i;
    float mx = -1e30f;
    for (int j = 0; j <= hi; ++j) mx = fmaxf(mx, s[i][j]);
    float sum = 0.f;
    for (int j = 0; j <= hi; ++j) {
      float e = __expf(s[i][j] - mx);
      s[i][j] = e;
      sum += e;
    }
    float inv = 1.0f / sum;
    for (int j = 0; j <= hi; ++j) s[i][j] *= inv;
  }
  __syncthreads();
  for (int idx = tid; idx < 20 * HD_; idx += 256) {
    int i = idx >> 6, d = idx & 63;
    int hi = r0 + i;
    float acc = 0.f;
    for (int j = 0; j <= hi; ++j) acc += s[i][j] * v[j][d];
    ctx[(long)(b * T_ + hi) * D_ + h * HD_ + d] = acc;
  }
}

// ---- fused pproj/cproj/weff (one launch, grid y-ranges), 32x32 staged -----
__global__ __launch_bounds__(256) void fuse3_k(
    const bf16* __restrict__ patb, const float* __restrict__ xbuf,
    const float* __restrict__ cls_w, const bf16* __restrict__ fusb,
    const bf16* __restrict__ w2Tb, const float* __restrict__ fus_b1,
    const int* __restrict__ tokens, float* __restrict__ pprojT,
    float* __restrict__ cw) {
  __shared__ bf16 As[32 * 72];
  __shared__ bf16 Ws[32 * 72];
  const int tid = threadIdx.x;
  const int lane = tid & 63;
  const int wv = tid >> 6;
  const int mi = wv & 1, ni = wv >> 1;
  const int col = lane & 15, quad = lane >> 4;
  const int bn = blockIdx.x * 32;
  const int y = blockIdx.y;
  const int srow = tid >> 3, kc = (tid & 7) * 8;

  int job, bm;
  if (y < 256) { job = 0; bm = y * 32; }
  else if (y < 296) { job = 1; bm = (y - 256) * 32; }
  else { job = 2; bm = (y - 296) * 32; }
  const int gm = bm + srow;

  const bf16* Wp;
  int K = D_;
  bool zeroA = false;
  const float* Apf = nullptr;
  const bf16* Apb = nullptr;
  if (job == 0) {
    Apb = patb + (long)gm * DINO_;
    Wp = fusb + (long)(bn + srow) * 640 + kc;
    K = DINO_;
  } else if (job == 1) {
    int t = gm % T_;
    zeroA = (t == 0);
    Apf = xbuf + (long)(zeroA ? gm : gm - 1) * D_;
    Wp = fusb + 384 + (long)(bn + srow) * 640 + kc;
  } else {
    Apf = cls_w + (long)tokens[gm] * D_;
    Wp = w2Tb + (long)(bn + srow) * D_ + kc;
  }

  f32x4 acc = {0.f, 0.f, 0.f, 0.f};
  bf16x8 z8 = {};
  for (int kk = 0; kk < K; kk += 64) {
    bf16x8 av;
    if (job == 0) av = *(const bf16x8*)(Apb + kk + kc);
    else if (zeroA) av = z8;
    else av = cvt8(Apf + kk + kc);
    *(bf16x8*)&As[srow * 72 + kc] = av;
    *(bf16x8*)&Ws[srow * 72 + kc] = *(const bf16x8*)(Wp + kk);
    __syncthreads();
#pragma unroll
    for (int ki = 0; ki < 2; ++ki) {
      bf16x8 afr = *(const bf16x8*)&As[(mi * 16 + col) * 72 + ki * 32 + quad * 8];
      bf16x8 bfr = *(const bf16x8*)&Ws[(ni * 16 + col) * 72 + ki * 32 + quad * 8];
      acc = __builtin_amdgcn_mfma_f32_16x16x32_bf16(afr, bfr, acc, 0, 0, 0);
    }
    __syncthreads();
  }
  const int n = bn + ni * 16 + col;
  if (job == 0) {
#pragma unroll
    for (int r4 = 0; r4 < 4; ++r4) {
      int m = bm + mi * 16 + quad * 4 + r4;
      int b = m >> 8, p = m & 255;
      pprojT[(long)b * (D_ * P_) + (long)n * P_ + p] = acc[r4];
    }
  } else if (job == 1) {
    float bv = fus_b1[n];
#pragma unroll
    for (int r4 = 0; r4 < 4; ++r4) {
      int m = bm + mi * 16 + quad * 4 + r4;
      cw[(long)m * (2 * D_) + n * 2] = acc[r4] + bv;
    }
  } else {
#pragma unroll
    for (int r4 = 0; r4 < 4; ++r4) {
      int m = bm + mi * 16 + quad * 4 + r4;
      cw[(long)m * (2 * D_) + n * 2 + 1] = acc[r4];
    }
  }
}

// ---- final: out[b,p,t] = sigmoid(sum_e gelu(pp+cp)*we + beff) -------------
__global__ __launch_bounds__(256) void final_k(const float* __restrict__ pprojT,
                                               const float* __restrict__ cw,
                                               const int* __restrict__ tokens,
                                               const float* __restrict__ cls_w,
                                               const float* __restrict__ cls_b,
                                               const float* __restrict__ fus_b2,
                                               float* __restrict__ out) {
  __shared__ float2 cws[4][D_];
  int tid = threadIdx.x;
  int lane = tid & 63, wv = tid >> 6;
  int p = blockIdx.x * 64 + lane;
  int t = blockIdx.y * 4 + wv;
  int b = blockIdx.z;
  int mbase = b * T_ + blockIdx.y * 4;
  for (int idx = tid; idx < 4 * D_; idx += 256) {
    int tt = idx >> 8, e = idx & 255;
    cws[tt][e] = ((const float2*)cw)[(long)(mbase + tt) * D_ + e];
  }
  __syncthreads();

  int m = b * T_ + t;
  int tok = tokens[m];
  const float* cr = cls_w + (long)tok * D_;
  float bacc = 0.f;
#pragma unroll
  for (int i = 0; i < 4; ++i) bacc += cr[lane + i * 64] * fus_b2[lane + i * 64];
#pragma unroll
  for (int mk = 1; mk < 64; mk <<= 1) bacc += __shfl_xor(bacc, mk);
  float beff = bacc + cls_b[tok];

  const float* ppb = pprojT + (long)b * (D_ * P_);  // [e][p]
  float acc = 0.f;
#pragma unroll 8
  for (int e = 0; e < D_; ++e) {
    float pp = ppb[e * P_ + p];
    float2 c = cws[wv][e];
    float x = pp + c.x;
    float x2 = x * x;
    float u = x * fmaf(-0.1029432f, x2, -2.3022083f);  // -log2e*1.5958*(x+0.044715x^3)
    float ex = __builtin_amdgcn_exp2f(u);
    float r = __builtin_amdgcn_rcpf(1.0f + ex);
    acc = fmaf(x * r, c.y, acc);
  }
  float logit = acc + beff;
  float es = __builtin_amdgcn_exp2f(-1.4426950408889634f * logit);
  out[(long)(b * P_ + p) * T_ + t] = __builtin_amdgcn_rcpf(1.0f + es);
}

extern "C" void kernel_launch(void* const* d_in, const int* in_sizes, int n_in, void* d_out,
                              int out_size, void* d_ws, size_t ws_size, hipStream_t stream) {
  const float* patches = (const float*)d_in[0];
  const int* tokens = (const int*)d_in[1];
  const float* tok_emb = (const float*)d_in[2];
  const float* pos_emb = (const float*)d_in[3];
  const float* qkv_w = (const float*)d_in[4];
  const float* qkv_b = (const float*)d_in[5];
  const float* out_w = (const float*)d_in[6];
  const float* out_b = (const float*)d_in[7];
  const float* ln1_s = (const float*)d_in[8];
  const float* ln1_b = (const float*)d_in[9];
  const float* w1 = (const float*)d_in[10];
  const float* b1 = (const float*)d_in[11];
  const float* w2 = (const float*)d_in[12];
  const float* b2 = (const float*)d_in[13];
  const float* ln2_s = (const float*)d_in[14];
  const float* ln2_b = (const float*)d_in[15];
  const float* fus_w1 = (const float*)d_in[16];
  const float* fus_b1 = (const float*)d_in[17];
  const float* fus_w2 = (const float*)d_in[18];
  const float* fus_b2 = (const float*)d_in[19];
  const float* cls_w = (const float*)d_in[20];
  const float* cls_b = (const float*)d_in[21];
  float* out = (float*)d_out;

  const int MT = B_ * T_;  // 1280
  float* x = (float*)d_ws;                     // 1280*256 (embed -> LN outs)
  float* qkvbuf = x + MT * D_;                 // 1280*768
  float* attbuf = qkvbuf + MT * 3 * D_;        // 1280*256
  float* s = attbuf + MT * D_;                 // 1280*256 (residual sums)
  float* pprojT = s + MT * D_;                 // 32*256*256 [b][e][p]
  float* cwbuf = pprojT + (long)B_ * D_ * P_;  // 1280*512 {cproj,weff}
  bf16* wb = (bf16*)(cwbuf + MT * D_ * 2);     // bf16 weight arena
  bf16* w2Tb = wb + WB_TOTAL;                  // 256*256
  bf16* patb = w2Tb + D_ * D_;                 // 32*256*384
  bf16* hb = patb + (long)B_ * P_ * DINO_;     // 1280*1024 bf16

  prep_k<<<MT + 64 + CONV_BLOCKS + PAT_BLOCKS, 256, 0, stream>>>(
      tokens, tok_emb, pos_emb, x, fus_w2, w2Tb, qkv_w, out_w, w1, w2, fus_w1, wb,
      patches, patb);

  for (int l = 0; l < L_; ++l) {
    // qkv = x @ qkv_w^T + qkv_b
    gemm_k<0, 0, 0, 0><<<dim3(24, 40), 256, 0, stream>>>(
        x, wb + OFF_QKV + (long)l * 3 * D_ * D_, qkv_b + l * 3 * D_, nullptr, qkvbuf,
        D_, D_, D_, 3 * D_);
    attn_k<<<dim3(H_, B_, 2), 256, 0, stream>>>(qkvbuf, attbuf);
    // s = att @ out_w^T + out_b + x
    gemm_k<0, 0, 0, 1><<<dim3(8, 40), 256, 0, stream>>>(
        attbuf, wb + OFF_OUTW + (long)l * D_ * D_, out_b + l * D_, x, s, D_, D_, D_, D_);
    // x = LN1(s)
    ln_k<<<MT / 4, 256, 0, stream>>>(s, x, ln1_s + l * D_, ln1_b + l * D_);
    // hb = relu(x @ w1^T + b1)  (bf16 out)
    gemm_k<0, 1, 1, 0><<<dim3(32, 40), 256, 0, stream>>>(
        x, wb + OFF_W1 + (long)l * DFF_ * D_, b1 + l * DFF_, nullptr, hb, D_, D_, D_, DFF_);
    // s = hb @ w2^T + b2 + x
    gemm_k<1, 0, 0, 1><<<dim3(8, 40), 256, 0, stream>>>(
        hb, wb + OFF_W2 + (long)l * D_ * DFF_, b2 + l * D_, x, s, DFF_, DFF_, DFF_, D_);
    // x = LN2(s)
    ln_k<<<MT / 4, 256, 0, stream>>>(s, x, ln2_s + l * D_, ln2_b + l * D_);
  }

  fuse3_k<<<dim3(8, 336), 256, 0, stream>>>(patb, x, cls_w, wb + OFF_FUS, w2Tb,
                                            fus_b1, tokens, pprojT, cwbuf);

  final_k<<<dim3(4, 10, 32), 256, 0, stream>>>(pprojT, cwbuf, tokens, cls_w, cls_b,
                                               fus_b2, out);
}